// Round 12
// baseline (278.891 us; speedup 1.0000x reference)
//
#include <hip/hip_runtime.h>
#include <hip/hip_bf16.h>
#include <stdint.h>

#define SEQ   4096
#define DM    128
#define KVB   64

typedef __attribute__((ext_vector_type(8)))  short  bf16x8;
typedef __attribute__((ext_vector_type(16))) float  f32x16;

// (1/sqrt(128)) * log2(e): folded into Wq so logits are already in exp2 domain
#define SCALE_LOG2E 0.12751743f

__device__ __forceinline__ f32x16 mfma_32x32x16(bf16x8 a, bf16x8 b, f32x16 c) {
  return __builtin_amdgcn_mfma_f32_32x32x16_bf16(a, b, c, 0, 0, 0);
}

__device__ __forceinline__ void gload16(const void* g, void* l) {
  __builtin_amdgcn_global_load_lds(
      (const __attribute__((address_space(1))) unsigned int*)g,
      (__attribute__((address_space(3))) unsigned int*)l, 16, 0, 0);
}

__device__ __forceinline__ unsigned pack2bf(float a, float b) {
  float2 t; t.x = a; t.y = b;
  __hip_bfloat162 h = __float22bfloat162_rn(t);
  union { __hip_bfloat162 h2; unsigned u; } cv;
  cv.h2 = h;
  return cv.u;
}

__device__ __forceinline__ float us2f(unsigned short u) {
  union { unsigned int i; float f; } c; c.i = ((unsigned)u) << 16; return c.f;
}

__device__ __forceinline__ float fast_exp2(float x) {
#if defined(__has_builtin)
#if __has_builtin(__builtin_amdgcn_exp2f)
  return __builtin_amdgcn_exp2f(x);
#else
  return exp2f(x);
#endif
#else
  return exp2f(x);
#endif
}

#define SBAR() __builtin_amdgcn_sched_barrier(0)

// ---------------------------------------------------------------------------
// Kernel 0: repack weights fp32 -> bf16 in MFMA B-fragment order.
// ---------------------------------------------------------------------------
__global__ void prep_w(const float* __restrict__ Wq, const float* __restrict__ Wk,
                       const float* __restrict__ Wv, __hip_bfloat16* __restrict__ Wb) {
  int t = blockIdx.x * 256 + threadIdx.x;
  if (t >= 12 * 8 * 64) return;
  int ct  = t >> 9;
  int rem = t & 511;
  int s   = rem >> 6;
  int l   = rem & 63;
  const float* W = (ct < 4) ? Wq : (ct < 8) ? Wk : Wv;
  float c = (ct < 4) ? SCALE_LOG2E : 1.0f;
  int h  = (ct & 3) * 32 + (l & 31);
  int d0 = 16 * s + 8 * (l >> 5);
  union { __hip_bfloat16 h8[8]; bf16x8 v; } u;
#pragma unroll
  for (int i = 0; i < 8; ++i) u.h8[i] = __float2bfloat16(W[(d0 + i) * DM + h] * c);
  *(bf16x8*)&Wb[(size_t)t * 8] = u.v;
}

// ---------------------------------------------------------------------------
// Kernel 1: QKV projection (unchanged; ~10 us).
// ---------------------------------------------------------------------------
__global__ void __launch_bounds__(256, 2)
proj(const float* __restrict__ x, const __hip_bfloat16* __restrict__ Wb,
     __hip_bfloat16* __restrict__ qw, __hip_bfloat16* __restrict__ kw,
     __hip_bfloat16* __restrict__ vtw) {
  __shared__ __hip_bfloat16 slab[4][1024];
  const int wave = threadIdx.x >> 6, lane = threadIdx.x & 63;
  const int l31 = lane & 31, hi = lane >> 5;
  const int t0 = blockIdx.x * 128 + wave * 32;
  const int trow = t0 + l31;

  bf16x8 af[8];
#pragma unroll
  for (int s = 0; s < 8; ++s) {
    const float* px = x + (size_t)trow * DM + 16 * s + 8 * hi;
    float4 u0 = *(const float4*)px;
    float4 u1 = *(const float4*)(px + 4);
    union { bf16x8 v; unsigned u[4]; } fr;
    fr.u[0] = pack2bf(u0.x, u0.y);
    fr.u[1] = pack2bf(u0.z, u0.w);
    fr.u[2] = pack2bf(u1.x, u1.y);
    fr.u[3] = pack2bf(u1.z, u1.w);
    af[s] = fr.v;
  }

  for (int ct = 0; ct < 12; ++ct) {
    f32x16 acc;
#pragma unroll
    for (int j = 0; j < 16; ++j) acc[j] = 0.f;
#pragma unroll
    for (int s = 0; s < 8; ++s) {
      bf16x8 bfr = *(const bf16x8*)&Wb[(size_t)((ct * 8 + s) * 64 + lane) * 8];
      acc = mfma_32x32x16(af[s], bfr, acc);
    }
    __syncthreads();
#pragma unroll
    for (int j = 0; j < 16; ++j) {
      int r = (j & 3) + 8 * (j >> 2) + 4 * hi;
      slab[wave][r * 32 + l31] = __float2bfloat16(acc[j]);
    }
    __syncthreads();
    if (ct < 8) {
      __hip_bfloat16* dst = (ct < 4) ? qw : kw;
      int hb = (ct & 3) * 32;
#pragma unroll
      for (int p = 0; p < 2; ++p) {
        int eidx = p * 512 + lane * 8;
        int tr = eidx >> 5, c = eidx & 31;
        *(bf16x8*)&dst[(size_t)(t0 + tr) * DM + hb + c] =
            *(const bf16x8*)&slab[wave][eidx];
      }
    } else {
      int d  = lane >> 1;
      int th = (lane & 1) * 16;
      int dg = (ct & 3) * 32 + d;
      int bb = t0 >> 12;
      int tl = t0 & 4095;
      __hip_bfloat16* dst = vtw + ((size_t)bb * DM + dg) * SEQ + tl + th;
#pragma unroll
      for (int k = 0; k < 4; ++k) {
        union { unsigned short u4[4]; uint2 v; } pkv;
#pragma unroll
        for (int e = 0; e < 4; ++e) {
          union { __hip_bfloat16 hh; unsigned short us; } cv;
          cv.hh = slab[wave][(th + 4 * k + e) * 32 + d];
          pkv.u4[e] = cv.us;
        }
        *(uint2*)&dst[4 * k] = pkv.v;
      }
    }
  }
}

// ---------------------------------------------------------------------------
// Kernel 2: causal flash attention, 16-WAVE BLOCKS (1024 thr) = 4 waves/SIMD
//   guaranteed by block shape (NO launch_bounds min-waves: R10 showed the
//   compiler caps VGPR to 64 and spills -> 565MB scratch traffic).
//   grid 256 = 1 block/CU; q-tiles of 512 rows (wave w owns rows w*32..+32);
//   16 waves share one K/V stage (1 gload16/thread per tile).
//   EQUAL 18-ITER JOBS: per batch, pair hi=7-g with lo=g: (64-8g)+(8g+8)=72
//   = 4 chunks x 18.  Piece bookkeeping (no-max softmax => pure sums):
//     first piece of tile -> raw f32 -> OUT (+lsumF)
//     later pieces        -> bf16 partial slot (+lsumS); whole tile -> direct.
//   Slots/batch: q7:3 q6:3 q5:2 q4:2 q3:1 q2:1 = 12.  merge sums+normalizes.
//   K 3-buf (dist 2), V 2-buf; 1 load/thread/stage; vmcnt(1) in-loop.
// ---------------------------------------------------------------------------
__device__ __forceinline__ void stage_k(const char* kb, int tile, char* kdst,
                                        int tid) {
  const char* ksrc = kb + (size_t)tile * (KVB * 256);  // 64 rows x 256B
  int row = tid >> 4, cb = (tid & 15) << 4;
  int col = cb ^ ((row & 15) << 4);
  gload16(ksrc + row * 256 + col, kdst + tid * 16);
}

__device__ __forceinline__ void stage_v(const char* vb, int tile, char* vdst,
                                        int tid) {
  const char* vsrc = vb + (size_t)tile * (KVB * 2);    // 64 tokens x 2B, d-major
  int row = tid >> 4, cb = (tid & 15) << 4;
  int col = cb ^ ((row & 15) << 4);
  size_t so = (size_t)(2 * row + (col >> 7)) * 8192 + (size_t)(col & 127);
  gload16(vsrc + so, vdst + tid * 16);
}

__global__ void __launch_bounds__(1024)
attn(const __hip_bfloat16* __restrict__ qw, const __hip_bfloat16* __restrict__ kw,
     const __hip_bfloat16* __restrict__ vtw, float* __restrict__ out,
     float* __restrict__ lsumF, float* __restrict__ lsumS,
     __hip_bfloat16* __restrict__ partS) {
  __shared__ __align__(16) char lds[81920];  // K:3x16K @0, V:2x16K @48K
  const int bid = blockIdx.x;
  const int xcd = bid & 7;
  const int b   = xcd + 8 * ((bid >> 3) & 1);  // XCD-pinned: 2 batches/XCD
  const int s   = (bid >> 4) & 3;              // chunk within group
  const int g   = bid >> 6;                    // group 0..3
  const int hiq = 7 - g, loq = g;
  const int Lh  = 64 - 8 * g;                  // hi tile iters
  const int Ll  = 8 * g + 8;                   // lo tile iters

  const int wave = threadIdx.x >> 6, lane = threadIdx.x & 63;
  const int l31 = lane & 31, hi = lane >> 5;
  const int tid = threadIdx.x;

  const char* kb = (const char*)(kw + (size_t)b * SEQ * DM);
  const char* vb = (const char*)(vtw + (size_t)b * DM * SEQ);

  char* k_cur = lds;         char* k_nxt = lds + 16384; char* k_nn = lds + 32768;
  char* v_cur = lds + 49152; char* v_nxt = lds + 65536;

  // mode 0: normalized->out; 1: raw f32->out (+lsumF); 2: bf16->slot (+lsumS)
  auto visit = [&](int qt, int t0, int cnt, int mode, int slot) {
    const int q0 = qt << 9;                       // 512-row tiles
    const int qrow = q0 + wave * 32 + l31;
    const int qminw = q0 + wave * 32;
    const int qmaxw = qminw + 31;

    bf16x8 qf[8];
    {
      const __hip_bfloat16* qb = qw + ((size_t)b * SEQ + qrow) * DM;
#pragma unroll
      for (int ss = 0; ss < 8; ++ss) qf[ss] = *(const bf16x8*)&qb[16 * ss + 8 * hi];
    }
    f32x16 yacc[4];
#pragma unroll
    for (int dt = 0; dt < 4; ++dt)
#pragma unroll
      for (int jj = 0; jj < 16; ++jj) yacc[dt][jj] = 0.f;
    f32x16 psum;
#pragma unroll
    for (int jj = 0; jj < 16; ++jj) psum[jj] = 0.f;

    // prologue: K(t0), V(t0), K(t0+1) in flight; vmcnt(1) -> K(t0),V(t0) landed.
    stage_k(kb, t0, k_cur, tid);
    stage_v(vb, t0, v_cur, tid);
    stage_k(kb, (cnt > 1 ? t0 + 1 : t0), k_nxt, tid);
    SBAR();
    asm volatile("s_waitcnt vmcnt(1)" ::: "memory");
    __builtin_amdgcn_s_barrier();
    SBAR();

    for (int u = 0; u < cnt; ++u) {
      const int t  = t0 + u;
      const int uv = (u + 1 < cnt) ? u + 1 : cnt - 1;
      const int uk = (u + 2 < cnt) ? u + 2 : cnt - 1;
      stage_v(vb, t0 + uv, v_nxt, tid);
      stage_k(kb, t0 + uk, k_nn, tid);

      const int kv0 = t * KVB;
      if (kv0 <= qmaxw) {
        // S^T = K @ Q^T for 2 key-subtiles of 32
        f32x16 sa, sb;
#pragma unroll
        for (int jj = 0; jj < 16; ++jj) { sa[jj] = 0.f; sb[jj] = 0.f; }
        __builtin_amdgcn_s_setprio(1);
#pragma unroll
        for (int ss = 0; ss < 8; ++ss) {
          int cbs = 32 * ss + 16 * hi;
          int r0 = l31, r1 = l31 + 32;
          bf16x8 k0 = *(const bf16x8*)&k_cur[r0 * 256 + (cbs ^ ((r0 & 15) << 4))];
          bf16x8 k1 = *(const bf16x8*)&k_cur[r1 * 256 + (cbs ^ ((r1 & 15) << 4))];
          sa = mfma_32x32x16(k0, qf[ss], sa);
          sb = mfma_32x32x16(k1, qf[ss], sb);
        }
        __builtin_amdgcn_s_setprio(0);
        // causal mask (diagonal tiles only); key row = (j&3)+8*(j>>2)+4*hi
        if (kv0 + 63 > qminw) {
#pragma unroll
          for (int jj = 0; jj < 16; ++jj) {
            int rr = (jj & 3) + 8 * (jj >> 2) + 4 * hi;
            sa[jj] = (kv0 + rr      > qrow) ? -1e30f : sa[jj];
            sb[jj] = (kv0 + 32 + rr > qrow) ? -1e30f : sb[jj];
          }
        }
        // no-max softmax: P = exp2(S) directly; normalization deferred.
#pragma unroll
        for (int jj = 0; jj < 16; ++jj) sa[jj] = fast_exp2(sa[jj]);
#pragma unroll
        for (int jj = 0; jj < 16; ++jj) sb[jj] = fast_exp2(sb[jj]);
#pragma unroll
        for (int jj = 0; jj < 16; ++jj) psum[jj] += sa[jj] + sb[jj];

        // PV: Y^T += V^T @ P^T; cross-half exchange via v_permlane32_swap_b32
#pragma unroll
        for (int a = 0; a < 2; ++a) {
          unsigned pk[8];
#pragma unroll
          for (int jj = 0; jj < 8; ++jj) {
            float lo  = a ? sb[2 * jj]     : sa[2 * jj];
            float hi2 = a ? sb[2 * jj + 1] : sa[2 * jj + 1];
            pk[jj] = pack2bf(lo, hi2);
          }
#pragma unroll
          for (int s2 = 0; s2 < 2; ++s2) {
            int base = 4 * s2;
            unsigned a0 = pk[base + 0], b0 = pk[base + 2];
            unsigned a1 = pk[base + 1], b1 = pk[base + 3];
            asm volatile("v_permlane32_swap_b32 %0, %1" : "+v"(a0), "+v"(b0));
            asm volatile("v_permlane32_swap_b32 %0, %1" : "+v"(a1), "+v"(b1));
            union { bf16x8 v; unsigned u[4]; } pf;
            pf.u[0] = a0;
            pf.u[1] = a1;
            pf.u[2] = b0;
            pf.u[3] = b1;
            __builtin_amdgcn_s_setprio(1);
#pragma unroll
            for (int dt = 0; dt < 4; ++dt) {
              int vrow = (l31 >> 1) + 16 * dt;
              int vcol = (l31 & 1) * 128 + 64 * a + 32 * s2 + 16 * hi;
              bf16x8 vf = *(const bf16x8*)&v_cur[vrow * 256 +
                                                 (vcol ^ ((vrow & 15) << 4))];
              yacc[dt] = mfma_32x32x16(vf, pf.v, yacc[dt]);
            }
            __builtin_amdgcn_s_setprio(0);
          }
        }
      }
      // counted-vmcnt barrier: V(t+1),K(t+1) landed; K(t+2) stays in flight.
      SBAR();
      asm volatile("s_waitcnt vmcnt(1)" ::: "memory");
      __builtin_amdgcn_s_barrier();
      SBAR();
      char* tmp = k_cur; k_cur = k_nxt; k_nxt = k_nn; k_nn = tmp;
      tmp = v_cur; v_cur = v_nxt; v_nxt = tmp;
    }
    // drain leftover prefetches before next visit re-stages the buffers.
    SBAR();
    asm volatile("s_waitcnt vmcnt(0)" ::: "memory");
    __builtin_amdgcn_s_barrier();
    SBAR();

    // lsum = reduce(psum) + cross-half
    float lsum = 0.f;
#pragma unroll
    for (int jj = 0; jj < 16; ++jj) lsum += psum[jj];
    lsum += __shfl_xor(lsum, 32);

    float* ob = out + ((size_t)b * SEQ + qrow) * DM;
    const int row = wave * 32 + l31;   // 0..511 within tile
    if (mode == 0) {
      float inv = 1.0f / lsum;
#pragma unroll
      for (int dt = 0; dt < 4; ++dt) {
#pragma unroll
        for (int g2 = 0; g2 < 4; ++g2) {
          float4 v;
          v.x = yacc[dt][4 * g2 + 0] * inv;
          v.y = yacc[dt][4 * g2 + 1] * inv;
          v.z = yacc[dt][4 * g2 + 2] * inv;
          v.w = yacc[dt][4 * g2 + 3] * inv;
          *(float4*)&ob[32 * dt + 8 * g2 + 4 * hi] = v;
        }
      }
    } else if (mode == 1) {
#pragma unroll
      for (int dt = 0; dt < 4; ++dt) {
#pragma unroll
        for (int g2 = 0; g2 < 4; ++g2) {
          float4 v;
          v.x = yacc[dt][4 * g2 + 0];
          v.y = yacc[dt][4 * g2 + 1];
          v.z = yacc[dt][4 * g2 + 2];
          v.w = yacc[dt][4 * g2 + 3];
          *(float4*)&ob[32 * dt + 8 * g2 + 4 * hi] = v;
        }
      }
      if (hi == 0) lsumF[(b * 8 + qt) * 512 + row] = lsum;
    } else {
      __hip_bfloat16* pb = partS + ((size_t)slot * 512 + row) * DM;
#pragma unroll
      for (int dt = 0; dt < 4; ++dt) {
#pragma unroll
        for (int g2 = 0; g2 < 4; ++g2) {
          uint2 pv;
          pv.x = pack2bf(yacc[dt][4 * g2 + 0], yacc[dt][4 * g2 + 1]);
          pv.y = pack2bf(yacc[dt][4 * g2 + 2], yacc[dt][4 * g2 + 3]);
          *(uint2*)&pb[32 * dt + 8 * g2 + 4 * hi] = pv;
        }
      }
      if (hi == 0) lsumS[slot * 512 + row] = lsum;
    }
  };

  // slot base within batch: q2:0 q3:1 q4:2 q5:4 q6:6 q7:9  (12 slots/batch)
  auto sbase = [](int q) {
    return (q == 2) ? 0 : (q == 3) ? 1 : (q == 4) ? 2 : (q == 5) ? 4
         : (q == 6) ? 6 : 9;
  };

  const int g0 = 18 * s, g1 = g0 + 18;
  // hi-tile overlap
  if (g0 < Lh) {
    int cnt = ((g1 < Lh) ? g1 : Lh) - g0;
    int mode = (s == 0) ? 1 : 2;
    int slot = b * 12 + sbase(hiq) + (s - 1);
    visit(hiq, g0, cnt, mode, slot);
  }
  // lo-tile overlap
  if (g1 > Lh) {
    int st = (g0 > Lh) ? g0 : Lh;
    int t0 = st - Lh;
    int cnt = g1 - st;
    int mode = (t0 == 0 && cnt == Ll) ? 0 : ((t0 == 0) ? 1 : 2);
    int slot = b * 12 + sbase(loq);   // lo tiles have at most 1 later piece
    visit(loq, t0, cnt, mode, slot);
  }
}

// ---------------------------------------------------------------------------
// Kernel 3: merge split tiles (q=2..7): out = (f32(out) + sum(bf16 slots))
//           / (lsumF + sum(lsumS)).  512 rows x 128 d per tile.
// ---------------------------------------------------------------------------
__global__ void __launch_bounds__(512)
merge(float* __restrict__ out, const float* __restrict__ lsumF,
      const float* __restrict__ lsumS, const __hip_bfloat16* __restrict__ partS) {
  __shared__ float invls[512];
  const int blk = blockIdx.x;           // 96 = 16 b x 6 q
  const int b = blk / 6;
  const int q = (blk % 6) + 2;
  const int nsl = (q <= 3) ? 1 : (q <= 5) ? 2 : 3;
  const int s0 = b * 12 + ((q == 2) ? 0 : (q == 3) ? 1 : (q == 4) ? 2
                           : (q == 5) ? 4 : (q == 6) ? 6 : 9);
  const int tid = threadIdx.x;
  float ls = lsumF[(b * 8 + q) * 512 + tid];
  for (int p = 0; p < nsl; ++p) ls += lsumS[(s0 + p) * 512 + tid];
  invls[tid] = 1.0f / ls;
  __syncthreads();
  float4* o4 = (float4*)(out + ((size_t)b * SEQ + (size_t)q * 512) * DM);
#pragma unroll
  for (int k = 0; k < 32; ++k) {
    int e4 = tid + 512 * k;             // 512 rows x 32 float4/row = 16384
    int row = e4 >> 5;
    float4 r = o4[e4];
    for (int p = 0; p < nsl; ++p) {
      const __hip_bfloat16* pb = partS + (size_t)(s0 + p) * 512 * DM;
      union { uint2 v; unsigned short sh[4]; } pv;
      pv.v = *(const uint2*)&pb[e4 * 4];
      r.x += us2f(pv.sh[0]);
      r.y += us2f(pv.sh[1]);
      r.z += us2f(pv.sh[2]);
      r.w += us2f(pv.sh[3]);
    }
    float inv = invls[row];
    r.x *= inv; r.y *= inv; r.z *= inv; r.w *= inv;
    o4[e4] = r;
  }
}

extern "C" void kernel_launch(void* const* d_in, const int* in_sizes, int n_in,
                              void* d_out, int out_size, void* d_ws, size_t ws_size,
                              hipStream_t stream) {
  const float* x  = (const float*)d_in[0];
  const float* Wq = (const float*)d_in[1];
  const float* Wk = (const float*)d_in[2];
  const float* Wv = (const float*)d_in[3];
  float* out = (float*)d_out;

  char* ws = (char*)d_ws;
  __hip_bfloat16* qw    = (__hip_bfloat16*)(ws);
  __hip_bfloat16* kw    = (__hip_bfloat16*)(ws + (size_t)16 * 1024 * 1024);
  __hip_bfloat16* vtw   = (__hip_bfloat16*)(ws + (size_t)32 * 1024 * 1024);
  char* base48 = ws + (size_t)48 * 1024 * 1024;
  __hip_bfloat16* Wb    = (__hip_bfloat16*)(base48);                       // 96KB
  float*          lsumF = (float*)(base48 + (size_t)1 * 1024 * 1024);      // 256KB
  float*          lsumS = (float*)(base48 + (size_t)2 * 1024 * 1024);      // 384KB
  __hip_bfloat16* partS = (__hip_bfloat16*)(base48 + (size_t)3 * 1024 * 1024); // 24MB
  // total ws use: 48MB + 3MB + 24MB = 75MB (R10 proved this allocation fits)

  prep_w<<<24, 256, 0, stream>>>(Wq, Wk, Wv, Wb);
  proj<<<512, 256, 0, stream>>>(x, Wb, qw, kw, vtw);
  attn<<<256, 1024, 0, stream>>>(qw, kw, vtw, out, lsumF, lsumS, partS);
  merge<<<96, 512, 0, stream>>>(out, lsumF, lsumS, partS);
}

// Round 13
// 153.688 us; speedup vs baseline: 1.8147x; 1.8147x over previous
//
#include <hip/hip_runtime.h>
#include <hip/hip_bf16.h>
#include <stdint.h>

#define SEQ   4096
#define DM    128
#define KVB   64

typedef __attribute__((ext_vector_type(8)))  short  bf16x8;
typedef __attribute__((ext_vector_type(16))) float  f32x16;

// (1/sqrt(128)) * log2(e): folded into Wq so logits are already in exp2 domain
#define SCALE_LOG2E 0.12751743f

__device__ __forceinline__ f32x16 mfma_32x32x16(bf16x8 a, bf16x8 b, f32x16 c) {
  return __builtin_amdgcn_mfma_f32_32x32x16_bf16(a, b, c, 0, 0, 0);
}

__device__ __forceinline__ void gload16(const void* g, void* l) {
  __builtin_amdgcn_global_load_lds(
      (const __attribute__((address_space(1))) unsigned int*)g,
      (__attribute__((address_space(3))) unsigned int*)l, 16, 0, 0);
}

__device__ __forceinline__ unsigned pack2bf(float a, float b) {
  float2 t; t.x = a; t.y = b;
  __hip_bfloat162 h = __float22bfloat162_rn(t);
  union { __hip_bfloat162 h2; unsigned u; } cv;
  cv.h2 = h;
  return cv.u;
}

__device__ __forceinline__ float us2f(unsigned short u) {
  union { unsigned int i; float f; } c; c.i = ((unsigned)u) << 16; return c.f;
}

__device__ __forceinline__ float fast_exp2(float x) {
#if defined(__has_builtin)
#if __has_builtin(__builtin_amdgcn_exp2f)
  return __builtin_amdgcn_exp2f(x);
#else
  return exp2f(x);
#endif
#else
  return exp2f(x);
#endif
}

#define SBAR() __builtin_amdgcn_sched_barrier(0)

// ---------------------------------------------------------------------------
// Kernel 0: repack weights fp32 -> bf16 in MFMA B-fragment order.
// ---------------------------------------------------------------------------
__global__ void prep_w(const float* __restrict__ Wq, const float* __restrict__ Wk,
                       const float* __restrict__ Wv, __hip_bfloat16* __restrict__ Wb) {
  int t = blockIdx.x * 256 + threadIdx.x;
  if (t >= 12 * 8 * 64) return;
  int ct  = t >> 9;
  int rem = t & 511;
  int s   = rem >> 6;
  int l   = rem & 63;
  const float* W = (ct < 4) ? Wq : (ct < 8) ? Wk : Wv;
  float c = (ct < 4) ? SCALE_LOG2E : 1.0f;
  int h  = (ct & 3) * 32 + (l & 31);
  int d0 = 16 * s + 8 * (l >> 5);
  union { __hip_bfloat16 h8[8]; bf16x8 v; } u;
#pragma unroll
  for (int i = 0; i < 8; ++i) u.h8[i] = __float2bfloat16(W[(d0 + i) * DM + h] * c);
  *(bf16x8*)&Wb[(size_t)t * 8] = u.v;
}

// ---------------------------------------------------------------------------
// Kernel 1: QKV projection (unchanged; ~10 us).
// ---------------------------------------------------------------------------
__global__ void __launch_bounds__(256, 2)
proj(const float* __restrict__ x, const __hip_bfloat16* __restrict__ Wb,
     __hip_bfloat16* __restrict__ qw, __hip_bfloat16* __restrict__ kw,
     __hip_bfloat16* __restrict__ vtw) {
  __shared__ __hip_bfloat16 slab[4][1024];
  const int wave = threadIdx.x >> 6, lane = threadIdx.x & 63;
  const int l31 = lane & 31, hi = lane >> 5;
  const int t0 = blockIdx.x * 128 + wave * 32;
  const int trow = t0 + l31;

  bf16x8 af[8];
#pragma unroll
  for (int s = 0; s < 8; ++s) {
    const float* px = x + (size_t)trow * DM + 16 * s + 8 * hi;
    float4 u0 = *(const float4*)px;
    float4 u1 = *(const float4*)(px + 4);
    union { bf16x8 v; unsigned u[4]; } fr;
    fr.u[0] = pack2bf(u0.x, u0.y);
    fr.u[1] = pack2bf(u0.z, u0.w);
    fr.u[2] = pack2bf(u1.x, u1.y);
    fr.u[3] = pack2bf(u1.z, u1.w);
    af[s] = fr.v;
  }

  for (int ct = 0; ct < 12; ++ct) {
    f32x16 acc;
#pragma unroll
    for (int j = 0; j < 16; ++j) acc[j] = 0.f;
#pragma unroll
    for (int s = 0; s < 8; ++s) {
      bf16x8 bfr = *(const bf16x8*)&Wb[(size_t)((ct * 8 + s) * 64 + lane) * 8];
      acc = mfma_32x32x16(af[s], bfr, acc);
    }
    __syncthreads();
#pragma unroll
    for (int j = 0; j < 16; ++j) {
      int r = (j & 3) + 8 * (j >> 2) + 4 * hi;
      slab[wave][r * 32 + l31] = __float2bfloat16(acc[j]);
    }
    __syncthreads();
    if (ct < 8) {
      __hip_bfloat16* dst = (ct < 4) ? qw : kw;
      int hb = (ct & 3) * 32;
#pragma unroll
      for (int p = 0; p < 2; ++p) {
        int eidx = p * 512 + lane * 8;
        int tr = eidx >> 5, c = eidx & 31;
        *(bf16x8*)&dst[(size_t)(t0 + tr) * DM + hb + c] =
            *(const bf16x8*)&slab[wave][eidx];
      }
    } else {
      int d  = lane >> 1;
      int th = (lane & 1) * 16;
      int dg = (ct & 3) * 32 + d;
      int bb = t0 >> 12;
      int tl = t0 & 4095;
      __hip_bfloat16* dst = vtw + ((size_t)bb * DM + dg) * SEQ + tl + th;
#pragma unroll
      for (int k = 0; k < 4; ++k) {
        union { unsigned short u4[4]; uint2 v; } pkv;
#pragma unroll
        for (int e = 0; e < 4; ++e) {
          union { __hip_bfloat16 hh; unsigned short us; } cv;
          cv.hh = slab[wave][(th + 4 * k + e) * 32 + d];
          pkv.u4[e] = cv.us;
        }
        *(uint2*)&dst[4 * k] = pkv.v;
      }
    }
  }
}

// ---------------------------------------------------------------------------
// Kernel 2: causal flash attention, 2 BLOCKS/CU (4 waves/SIMD) — resource math:
//   8-wave blocks, natural VGPR (~104-120, must be <=128), 80KB LDS.
//   2 blocks/CU: VGPR 4 waves/SIMD x 128 = 512 (pool exactly);
//   LDS 2 x 80KB = 160KB (exactly).  __launch_bounds__(512) with NO min-waves
//   arg: R10 (512,4) and R12 (1024) both made the compiler cap VGPR at 64 ->
//   yacc spilled -> 470-565MB scratch traffic.  R9 proved (512) alone
//   compiles this body spill-free.
//   EQUAL 17-ITER JOBS (correctness-proven R11/R12): per batch, 8 groups pair
//   tile hi=15-g with lo=g ((4hi+4)+(4lo+4)=68=4x17); chunk s of [hi|lo].
//     first piece of a tile  -> raw f32 into OUT (+lsumF)
//     later pieces           -> bf16 partial into slot (+lsumS)
//     whole tile in one job  -> direct normalized write
//   Slots/batch: hi12-15:3ea, hi8-11:2ea, lo4-7:1ea = 24; merge sums them.
// ---------------------------------------------------------------------------
__device__ __forceinline__ void stage_k(const char* kb, int tile, char* kdst,
                                        int tid, int wave) {
  const char* ksrc = kb + (size_t)tile * (KVB * 256);  // 64 rows x 256B
#pragma unroll
  for (int p = 0; p < 2; ++p) {
    int lin = p * 8192 + tid * 16;
    int row = lin >> 8, cb = lin & 255;
    int col = cb ^ ((row & 15) << 4);
    gload16(ksrc + row * 256 + col, kdst + p * 8192 + (wave << 10));
  }
}

__device__ __forceinline__ void stage_v(const char* vb, int tile, char* vdst,
                                        int tid, int wave) {
  const char* vsrc = vb + (size_t)tile * (KVB * 2);    // 64 tokens x 2B, d-major
#pragma unroll
  for (int p = 0; p < 2; ++p) {
    int lin = p * 8192 + tid * 16;
    int row = lin >> 8, cb = lin & 255;
    int col = cb ^ ((row & 15) << 4);
    size_t so = (size_t)(2 * row + (col >> 7)) * 8192 + (size_t)(col & 127);
    gload16(vsrc + so, vdst + p * 8192 + (wave << 10));
  }
}

__global__ void __launch_bounds__(512)
attn(const __hip_bfloat16* __restrict__ qw, const __hip_bfloat16* __restrict__ kw,
     const __hip_bfloat16* __restrict__ vtw, float* __restrict__ out,
     float* __restrict__ lsumF, float* __restrict__ lsumS,
     __hip_bfloat16* __restrict__ partS) {
  __shared__ __align__(16) char lds[81920];  // K:3x16K @0, V:2x16K @48K
  const int bid = blockIdx.x;
  const int xcd = bid & 7;
  const int b   = xcd + 8 * ((bid >> 3) & 1);  // XCD-pinned: 2 batches/XCD
  const int s   = (bid >> 4) & 3;              // chunk within group
  const int g   = bid >> 6;                    // group 0..7
  const int hiq = 15 - g, loq = g;
  const int Lh  = 4 * hiq + 4;

  const int wave = threadIdx.x >> 6, lane = threadIdx.x & 63;
  const int l31 = lane & 31, hi = lane >> 5;
  const int tid = threadIdx.x;

  const char* kb = (const char*)(kw + (size_t)b * SEQ * DM);
  const char* vb = (const char*)(vtw + (size_t)b * DM * SEQ);

  char* k_cur = lds;         char* k_nxt = lds + 16384; char* k_nn = lds + 32768;
  char* v_cur = lds + 49152; char* v_nxt = lds + 65536;

  // mode 0: normalized->out; 1: raw f32->out (+lsumF); 2: bf16->slot (+lsumS)
  auto visit = [&](int qt, int t0, int cnt, int mode, int slot) {
    const int q0 = qt << 8;                       // 256-row tiles
    const int qrow = q0 + wave * 32 + l31;
    const int qminw = q0 + wave * 32;
    const int qmaxw = qminw + 31;

    bf16x8 qf[8];
    {
      const __hip_bfloat16* qb = qw + ((size_t)b * SEQ + qrow) * DM;
#pragma unroll
      for (int ss = 0; ss < 8; ++ss) qf[ss] = *(const bf16x8*)&qb[16 * ss + 8 * hi];
    }
    f32x16 yacc[4];
#pragma unroll
    for (int dt = 0; dt < 4; ++dt)
#pragma unroll
      for (int jj = 0; jj < 16; ++jj) yacc[dt][jj] = 0.f;
    f32x16 psum;
#pragma unroll
    for (int jj = 0; jj < 16; ++jj) psum[jj] = 0.f;

    // prologue: K(t0), V(t0), K(t0+1) in flight; wait until only K(t0+1) left.
    stage_k(kb, t0, k_cur, tid, wave);
    stage_v(vb, t0, v_cur, tid, wave);
    stage_k(kb, (cnt > 1 ? t0 + 1 : t0), k_nxt, tid, wave);
    SBAR();
    asm volatile("s_waitcnt vmcnt(2)" ::: "memory");
    __builtin_amdgcn_s_barrier();
    SBAR();

    for (int u = 0; u < cnt; ++u) {
      const int t  = t0 + u;
      const int uv = (u + 1 < cnt) ? u + 1 : cnt - 1;
      const int uk = (u + 2 < cnt) ? u + 2 : cnt - 1;
      stage_v(vb, t0 + uv, v_nxt, tid, wave);
      stage_k(kb, t0 + uk, k_nn, tid, wave);

      const int kv0 = t * KVB;
      if (kv0 <= qmaxw) {
        // S^T = K @ Q^T for 2 key-subtiles of 32
        f32x16 sa, sb;
#pragma unroll
        for (int jj = 0; jj < 16; ++jj) { sa[jj] = 0.f; sb[jj] = 0.f; }
        __builtin_amdgcn_s_setprio(1);
#pragma unroll
        for (int ss = 0; ss < 8; ++ss) {
          int cbs = 32 * ss + 16 * hi;
          int r0 = l31, r1 = l31 + 32;
          bf16x8 k0 = *(const bf16x8*)&k_cur[r0 * 256 + (cbs ^ ((r0 & 15) << 4))];
          bf16x8 k1 = *(const bf16x8*)&k_cur[r1 * 256 + (cbs ^ ((r1 & 15) << 4))];
          sa = mfma_32x32x16(k0, qf[ss], sa);
          sb = mfma_32x32x16(k1, qf[ss], sb);
        }
        __builtin_amdgcn_s_setprio(0);
        // causal mask (diagonal tiles only); key row = (j&3)+8*(j>>2)+4*hi
        if (kv0 + 63 > qminw) {
#pragma unroll
          for (int jj = 0; jj < 16; ++jj) {
            int rr = (jj & 3) + 8 * (jj >> 2) + 4 * hi;
            sa[jj] = (kv0 + rr      > qrow) ? -1e30f : sa[jj];
            sb[jj] = (kv0 + 32 + rr > qrow) ? -1e30f : sb[jj];
          }
        }
        // no-max softmax: P = exp2(S) directly; normalization deferred.
#pragma unroll
        for (int jj = 0; jj < 16; ++jj) sa[jj] = fast_exp2(sa[jj]);
#pragma unroll
        for (int jj = 0; jj < 16; ++jj) sb[jj] = fast_exp2(sb[jj]);
#pragma unroll
        for (int jj = 0; jj < 16; ++jj) psum[jj] += sa[jj] + sb[jj];

        // PV: Y^T += V^T @ P^T; cross-half exchange via v_permlane32_swap_b32
#pragma unroll
        for (int a = 0; a < 2; ++a) {
          unsigned pk[8];
#pragma unroll
          for (int jj = 0; jj < 8; ++jj) {
            float lo  = a ? sb[2 * jj]     : sa[2 * jj];
            float hi2 = a ? sb[2 * jj + 1] : sa[2 * jj + 1];
            pk[jj] = pack2bf(lo, hi2);
          }
#pragma unroll
          for (int s2 = 0; s2 < 2; ++s2) {
            int base = 4 * s2;
            unsigned a0 = pk[base + 0], b0 = pk[base + 2];
            unsigned a1 = pk[base + 1], b1 = pk[base + 3];
            asm volatile("v_permlane32_swap_b32 %0, %1" : "+v"(a0), "+v"(b0));
            asm volatile("v_permlane32_swap_b32 %0, %1" : "+v"(a1), "+v"(b1));
            union { bf16x8 v; unsigned u[4]; } pf;
            pf.u[0] = a0;
            pf.u[1] = a1;
            pf.u[2] = b0;
            pf.u[3] = b1;
            __builtin_amdgcn_s_setprio(1);
#pragma unroll
            for (int dt = 0; dt < 4; ++dt) {
              int vrow = (l31 >> 1) + 16 * dt;
              int vcol = (l31 & 1) * 128 + 64 * a + 32 * s2 + 16 * hi;
              bf16x8 vf = *(const bf16x8*)&v_cur[vrow * 256 +
                                                 (vcol ^ ((vrow & 15) << 4))];
              yacc[dt] = mfma_32x32x16(vf, pf.v, yacc[dt]);
            }
            __builtin_amdgcn_s_setprio(0);
          }
        }
      }
      // counted-vmcnt barrier: V(t+1),K(t+1) landed; K(t+2)'s 2 stay in flight.
      SBAR();
      asm volatile("s_waitcnt vmcnt(2)" ::: "memory");
      __builtin_amdgcn_s_barrier();
      SBAR();
      char* tmp = k_cur; k_cur = k_nxt; k_nxt = k_nn; k_nn = tmp;
      tmp = v_cur; v_cur = v_nxt; v_nxt = tmp;
    }
    // drain leftover prefetches before next visit re-stages the buffers.
    SBAR();
    asm volatile("s_waitcnt vmcnt(0)" ::: "memory");
    __builtin_amdgcn_s_barrier();
    SBAR();

    // lsum = reduce(psum) + cross-half
    float lsum = 0.f;
#pragma unroll
    for (int jj = 0; jj < 16; ++jj) lsum += psum[jj];
    lsum += __shfl_xor(lsum, 32);

    float* ob = out + ((size_t)b * SEQ + qrow) * DM;
    const int row = wave * 32 + l31;   // 0..255 within tile
    if (mode == 0) {
      float inv = 1.0f / lsum;
#pragma unroll
      for (int dt = 0; dt < 4; ++dt) {
#pragma unroll
        for (int g2 = 0; g2 < 4; ++g2) {
          float4 v;
          v.x = yacc[dt][4 * g2 + 0] * inv;
          v.y = yacc[dt][4 * g2 + 1] * inv;
          v.z = yacc[dt][4 * g2 + 2] * inv;
          v.w = yacc[dt][4 * g2 + 3] * inv;
          *(float4*)&ob[32 * dt + 8 * g2 + 4 * hi] = v;
        }
      }
    } else if (mode == 1) {
#pragma unroll
      for (int dt = 0; dt < 4; ++dt) {
#pragma unroll
        for (int g2 = 0; g2 < 4; ++g2) {
          float4 v;
          v.x = yacc[dt][4 * g2 + 0];
          v.y = yacc[dt][4 * g2 + 1];
          v.z = yacc[dt][4 * g2 + 2];
          v.w = yacc[dt][4 * g2 + 3];
          *(float4*)&ob[32 * dt + 8 * g2 + 4 * hi] = v;
        }
      }
      if (hi == 0) lsumF[(b * 16 + qt) * 256 + row] = lsum;
    } else {
      __hip_bfloat16* pb = partS + ((size_t)slot * 256 + row) * DM;
#pragma unroll
      for (int dt = 0; dt < 4; ++dt) {
#pragma unroll
        for (int g2 = 0; g2 < 4; ++g2) {
          uint2 pv;
          pv.x = pack2bf(yacc[dt][4 * g2 + 0], yacc[dt][4 * g2 + 1]);
          pv.y = pack2bf(yacc[dt][4 * g2 + 2], yacc[dt][4 * g2 + 3]);
          *(uint2*)&pb[32 * dt + 8 * g2 + 4 * hi] = pv;
        }
      }
      if (hi == 0) lsumS[slot * 256 + row] = lsum;
    }
  };

  // slot base within batch for tile q:
  //   q in [4,7]  -> q-4            (1 slot)
  //   q in [8,11] -> 4 + (q-8)*2    (2 slots)
  //   q in [12,15]-> 12 + (q-12)*3  (3 slots)
  auto slot_base = [](int q) {
    return (q <= 7) ? (q - 4) : (q <= 11) ? (4 + (q - 8) * 2) : (12 + (q - 12) * 3);
  };

  const int g0 = 17 * s, g1 = g0 + 17;
  // hi-tile overlap
  if (g0 < Lh) {
    int cnt = ((g1 < Lh) ? g1 : Lh) - g0;
    int mode = (g0 == 0) ? 1 : 2;
    int p = g0 / 17;                       // 1..3 for later pieces
    int slot = b * 24 + slot_base(hiq) + (p - 1);
    visit(hiq, g0, cnt, mode, slot);
  }
  // lo-tile overlap
  if (g1 > Lh) {
    int st = (g0 > Lh) ? g0 : Lh;
    int t0 = st - Lh;
    int cnt = g1 - st;
    int mode = (loq <= 3) ? 0 : ((t0 == 0) ? 1 : 2);
    int slot = b * 24 + slot_base(loq);    // lo tiles have exactly 1 extra piece
    visit(loq, t0, cnt, mode, slot);
  }
}

// ---------------------------------------------------------------------------
// Kernel 3: merge split tiles (q=4..15): out = (f32(out) + sum(bf16 slots))
//           / (lsumF + sum(lsumS)).
// ---------------------------------------------------------------------------
__global__ void __launch_bounds__(256)
merge(float* __restrict__ out, const float* __restrict__ lsumF,
      const float* __restrict__ lsumS, const __hip_bfloat16* __restrict__ partS) {
  __shared__ float invls[256];
  const int blk = blockIdx.x;           // 192 = 16 b x 12 q
  const int b = blk / 12;
  const int q = (blk % 12) + 4;
  const int nsl = (q <= 7) ? 1 : (q <= 11) ? 2 : 3;
  const int s0 = b * 24 + ((q <= 7) ? (q - 4) : (q <= 11) ? (4 + (q - 8) * 2)
                                               : (12 + (q - 12) * 3));
  const int tid = threadIdx.x;
  float ls = lsumF[(b * 16 + q) * 256 + tid];
  for (int p = 0; p < nsl; ++p) ls += lsumS[(s0 + p) * 256 + tid];
  invls[tid] = 1.0f / ls;
  __syncthreads();
  float4* o4 = (float4*)(out + ((size_t)b * SEQ + (size_t)q * 256) * DM);
#pragma unroll
  for (int k = 0; k < 32; ++k) {
    int e4 = tid + 256 * k;             // 256 rows x 32 float4/row
    int row = e4 >> 5;
    float4 r = o4[e4];
    for (int p = 0; p < nsl; ++p) {
      const __hip_bfloat16* pb = partS + (size_t)(s0 + p) * 256 * DM;
      union { uint2 v; unsigned short sh[4]; } pv;
      pv.v = *(const uint2*)&pb[e4 * 4];
      r.x += us2f(pv.sh[0]);
      r.y += us2f(pv.sh[1]);
      r.z += us2f(pv.sh[2]);
      r.w += us2f(pv.sh[3]);
    }
    float inv = invls[row];
    r.x *= inv; r.y *= inv; r.z *= inv; r.w *= inv;
    o4[e4] = r;
  }
}

extern "C" void kernel_launch(void* const* d_in, const int* in_sizes, int n_in,
                              void* d_out, int out_size, void* d_ws, size_t ws_size,
                              hipStream_t stream) {
  const float* x  = (const float*)d_in[0];
  const float* Wq = (const float*)d_in[1];
  const float* Wk = (const float*)d_in[2];
  const float* Wv = (const float*)d_in[3];
  float* out = (float*)d_out;

  char* ws = (char*)d_ws;
  __hip_bfloat16* qw    = (__hip_bfloat16*)(ws);
  __hip_bfloat16* kw    = (__hip_bfloat16*)(ws + (size_t)16 * 1024 * 1024);
  __hip_bfloat16* vtw   = (__hip_bfloat16*)(ws + (size_t)32 * 1024 * 1024);
  char* base48 = ws + (size_t)48 * 1024 * 1024;
  __hip_bfloat16* Wb    = (__hip_bfloat16*)(base48);                       // 96KB
  float*          lsumF = (float*)(base48 + (size_t)1 * 1024 * 1024);      // 256KB
  float*          lsumS = (float*)(base48 + (size_t)2 * 1024 * 1024);      // 384KB
  __hip_bfloat16* partS = (__hip_bfloat16*)(base48 + (size_t)3 * 1024 * 1024); // 24MB
  // total ws use: 48MB + 3MB + 24MB = 75MB (proven to fit in R10/R12)

  prep_w<<<24, 256, 0, stream>>>(Wq, Wk, Wv, Wb);
  proj<<<512, 256, 0, stream>>>(x, Wb, qw, kw, vtw);
  attn<<<512, 512, 0, stream>>>(qw, kw, vtw, out, lsumF, lsumS, partS);
  merge<<<192, 256, 0, stream>>>(out, lsumF, lsumS, partS);
}

// Round 14
// 120.163 us; speedup vs baseline: 2.3209x; 1.2790x over previous
//
#include <hip/hip_runtime.h>
#include <hip/hip_bf16.h>
#include <stdint.h>

#define SEQ   4096
#define DM    128
#define KVB   128

typedef __attribute__((ext_vector_type(8)))  short  bf16x8;
typedef __attribute__((ext_vector_type(16))) float  f32x16;

// (1/sqrt(128)) * log2(e): folded into Wq so logits are already in exp2 domain
#define SCALE_LOG2E 0.12751743f

__device__ __forceinline__ f32x16 mfma_32x32x16(bf16x8 a, bf16x8 b, f32x16 c) {
  return __builtin_amdgcn_mfma_f32_32x32x16_bf16(a, b, c, 0, 0, 0);
}

__device__ __forceinline__ void gload16(const void* g, void* l) {
  __builtin_amdgcn_global_load_lds(
      (const __attribute__((address_space(1))) unsigned int*)g,
      (__attribute__((address_space(3))) unsigned int*)l, 16, 0, 0);
}

__device__ __forceinline__ unsigned pack2bf(float a, float b) {
  float2 t; t.x = a; t.y = b;
  __hip_bfloat162 h = __float22bfloat162_rn(t);
  union { __hip_bfloat162 h2; unsigned u; } cv;
  cv.h2 = h;
  return cv.u;
}

__device__ __forceinline__ float us2f(unsigned short u) {
  union { unsigned int i; float f; } c; c.i = ((unsigned)u) << 16; return c.f;
}

__device__ __forceinline__ float fast_exp2(float x) {
#if defined(__has_builtin)
#if __has_builtin(__builtin_amdgcn_exp2f)
  return __builtin_amdgcn_exp2f(x);
#else
  return exp2f(x);
#endif
#else
  return exp2f(x);
#endif
}

#define SBAR() __builtin_amdgcn_sched_barrier(0)

// ---------------------------------------------------------------------------
// Kernel 0: repack weights fp32 -> bf16 in MFMA B-fragment order.
// ---------------------------------------------------------------------------
__global__ void prep_w(const float* __restrict__ Wq, const float* __restrict__ Wk,
                       const float* __restrict__ Wv, __hip_bfloat16* __restrict__ Wb) {
  int t = blockIdx.x * 256 + threadIdx.x;
  if (t >= 12 * 8 * 64) return;
  int ct  = t >> 9;
  int rem = t & 511;
  int s   = rem >> 6;
  int l   = rem & 63;
  const float* W = (ct < 4) ? Wq : (ct < 8) ? Wk : Wv;
  float c = (ct < 4) ? SCALE_LOG2E : 1.0f;
  int h  = (ct & 3) * 32 + (l & 31);
  int d0 = 16 * s + 8 * (l >> 5);
  union { __hip_bfloat16 h8[8]; bf16x8 v; } u;
#pragma unroll
  for (int i = 0; i < 8; ++i) u.h8[i] = __float2bfloat16(W[(d0 + i) * DM + h] * c);
  *(bf16x8*)&Wb[(size_t)t * 8] = u.v;
}

// ---------------------------------------------------------------------------
// Kernel 1: QKV projection (unchanged; ~10 us).
// ---------------------------------------------------------------------------
__global__ void __launch_bounds__(256, 2)
proj(const float* __restrict__ x, const __hip_bfloat16* __restrict__ Wb,
     __hip_bfloat16* __restrict__ qw, __hip_bfloat16* __restrict__ kw,
     __hip_bfloat16* __restrict__ vtw) {
  __shared__ __hip_bfloat16 slab[4][1024];
  const int wave = threadIdx.x >> 6, lane = threadIdx.x & 63;
  const int l31 = lane & 31, hi = lane >> 5;
  const int t0 = blockIdx.x * 128 + wave * 32;
  const int trow = t0 + l31;

  bf16x8 af[8];
#pragma unroll
  for (int s = 0; s < 8; ++s) {
    const float* px = x + (size_t)trow * DM + 16 * s + 8 * hi;
    float4 u0 = *(const float4*)px;
    float4 u1 = *(const float4*)(px + 4);
    union { bf16x8 v; unsigned u[4]; } fr;
    fr.u[0] = pack2bf(u0.x, u0.y);
    fr.u[1] = pack2bf(u0.z, u0.w);
    fr.u[2] = pack2bf(u1.x, u1.y);
    fr.u[3] = pack2bf(u1.z, u1.w);
    af[s] = fr.v;
  }

  for (int ct = 0; ct < 12; ++ct) {
    f32x16 acc;
#pragma unroll
    for (int j = 0; j < 16; ++j) acc[j] = 0.f;
#pragma unroll
    for (int s = 0; s < 8; ++s) {
      bf16x8 bfr = *(const bf16x8*)&Wb[(size_t)((ct * 8 + s) * 64 + lane) * 8];
      acc = mfma_32x32x16(af[s], bfr, acc);
    }
    __syncthreads();
#pragma unroll
    for (int j = 0; j < 16; ++j) {
      int r = (j & 3) + 8 * (j >> 2) + 4 * hi;
      slab[wave][r * 32 + l31] = __float2bfloat16(acc[j]);
    }
    __syncthreads();
    if (ct < 8) {
      __hip_bfloat16* dst = (ct < 4) ? qw : kw;
      int hb = (ct & 3) * 32;
#pragma unroll
      for (int p = 0; p < 2; ++p) {
        int eidx = p * 512 + lane * 8;
        int tr = eidx >> 5, c = eidx & 31;
        *(bf16x8*)&dst[(size_t)(t0 + tr) * DM + hb + c] =
            *(const bf16x8*)&slab[wave][eidx];
      }
    } else {
      int d  = lane >> 1;
      int th = (lane & 1) * 16;
      int dg = (ct & 3) * 32 + d;
      int bb = t0 >> 12;
      int tl = t0 & 4095;
      __hip_bfloat16* dst = vtw + ((size_t)bb * DM + dg) * SEQ + tl + th;
#pragma unroll
      for (int k = 0; k < 4; ++k) {
        union { unsigned short u4[4]; uint2 v; } pkv;
#pragma unroll
        for (int e = 0; e < 4; ++e) {
          union { __hip_bfloat16 hh; unsigned short us; } cv;
          cv.hh = slab[wave][(th + 4 * k + e) * 32 + d];
          pkv.u4[e] = cv.us;
        }
        *(uint2*)&dst[4 * k] = pkv.v;
      }
    }
  }
}

// ---------------------------------------------------------------------------
// Kernel 2: causal flash attention, KVB=128 (double barrier interval).
//   grid 256 x 512thr (8 waves), 1 block/CU, 256-row q-tiles (R8 geometry).
//   Per iter: stage K(t+1),V(t+1) at TOP (8 loads/thread) -> compute 128 keys
//   as two independent 64-key half-streams (PV(h0) and QK(h1) are independent
//   chains -> scheduler fills dependency bubbles) -> vmcnt(0)+barrier (drain
//   is free: loads were issued a whole compute-interval earlier).
//   Barrier count halves vs R8 (17 vs 34 per job).
//   LDS 128KB: K 2x32KB + V 2x32KB.  K tile [128 rows][256B] swizzled
//   byte^=(row&15)<<4; V tile [128 d][256B tokens] same swizzle.
//   EQUAL 17-ITER JOBS (KVB=128): per batch 16 jobs:
//     A(b,i): tile 15-i, iters [0,17)           -> raw f32 -> OUT (+lsumA)
//     B(b,i): tile 15-i, iters [17,32-2i)       -> bf16 partial (+lsumB)
//             then tile i, iters [0,2i+2)       -> direct normalized
// ---------------------------------------------------------------------------
__device__ __forceinline__ void stage_k(const char* kb, int tile, char* kdst,
                                        int tid) {
  const char* ksrc = kb + (size_t)tile * (KVB * 256);  // 128 rows x 256B
#pragma unroll
  for (int p = 0; p < 4; ++p) {
    int lin = p * 8192 + tid * 16;
    int row = lin >> 8, cb = lin & 255;
    int col = cb ^ ((row & 15) << 4);
    gload16(ksrc + row * 256 + col, kdst + lin);
  }
}

__device__ __forceinline__ void stage_v(const char* vb, int tile, char* vdst,
                                        int tid) {
  const char* vsrc = vb + (size_t)tile * (KVB * 2);    // 128 tokens x 2B, d-major
#pragma unroll
  for (int p = 0; p < 4; ++p) {
    int lin = p * 8192 + tid * 16;
    int row = lin >> 8, cb = lin & 255;                // row = d, cb = token byte
    int col = cb ^ ((row & 15) << 4);
    gload16(vsrc + (size_t)row * 8192 + col, vdst + lin);
  }
}

__global__ void __launch_bounds__(512)
attn(const __hip_bfloat16* __restrict__ qw, const __hip_bfloat16* __restrict__ kw,
     const __hip_bfloat16* __restrict__ vtw, float* __restrict__ out,
     float* __restrict__ lsumA, float* __restrict__ lsumB,
     __hip_bfloat16* __restrict__ partB) {
  __shared__ __align__(16) char lds[131072];  // K0,K1 @0/32K; V0,V1 @64K/96K
  const int bid = blockIdx.x;
  const int xcd = bid & 7;
  const int g   = bid >> 3;            // 0..31
  const int b   = xcd + 8 * (g & 1);   // XCD-pinned: 2 batches/XCD
  const int j16 = g >> 1;              // 0..15
  const int i   = j16 & 7;
  const int isB = j16 >> 3;
  const int bigQ = 15 - i;             // 256-row tiles
  const int m = b * 8 + i;             // partial slot

  const int wave = threadIdx.x >> 6, lane = threadIdx.x & 63;
  const int l31 = lane & 31, hi = lane >> 5;
  const int tid = threadIdx.x;

  const char* kb = (const char*)(kw + (size_t)b * SEQ * DM);
  const char* vb = (const char*)(vtw + (size_t)b * DM * SEQ);

  char* k_cur = lds;         char* k_nxt = lds + 32768;
  char* v_cur = lds + 65536; char* v_nxt = lds + 98304;

  // mode 0: normalized->out; 1: raw f32->out (+lsumA); 2: bf16->partB (+lsumB)
  auto visit = [&](int qt, int t0, int cnt, int mode) {
    const int q0 = qt << 8;
    const int qrow = q0 + wave * 32 + l31;
    const int qminw = q0 + wave * 32;
    const int qmaxw = qminw + 31;

    bf16x8 qf[8];
    {
      const __hip_bfloat16* qb = qw + ((size_t)b * SEQ + qrow) * DM;
#pragma unroll
      for (int ss = 0; ss < 8; ++ss) qf[ss] = *(const bf16x8*)&qb[16 * ss + 8 * hi];
    }
    f32x16 yacc[4];
#pragma unroll
    for (int dt = 0; dt < 4; ++dt)
#pragma unroll
      for (int jj = 0; jj < 16; ++jj) yacc[dt][jj] = 0.f;
    f32x16 psum;
#pragma unroll
    for (int jj = 0; jj < 16; ++jj) psum[jj] = 0.f;

    stage_k(kb, t0, k_cur, tid);
    stage_v(vb, t0, v_cur, tid);
    SBAR();
    asm volatile("s_waitcnt vmcnt(0)" ::: "memory");
    __builtin_amdgcn_s_barrier();
    SBAR();

    for (int u = 0; u < cnt; ++u) {
      const int t  = t0 + u;
      const int un = (u + 1 < cnt) ? u + 1 : u;   // clamped prefetch
      stage_k(kb, t0 + un, k_nxt, tid);
      stage_v(vb, t0 + un, v_nxt, tid);

      // two independent 64-key half-streams within one barrier interval
#pragma unroll
      for (int h = 0; h < 2; ++h) {
        const int kv0 = t * KVB + 64 * h;
        if (kv0 > qmaxw) continue;               // wave-uniform causal skip
        f32x16 sa, sb;
#pragma unroll
        for (int jj = 0; jj < 16; ++jj) { sa[jj] = 0.f; sb[jj] = 0.f; }
        __builtin_amdgcn_s_setprio(1);
#pragma unroll
        for (int ss = 0; ss < 8; ++ss) {
          int cbs = 32 * ss + 16 * hi;
          int r0 = 64 * h + l31, r1 = 64 * h + l31 + 32;
          bf16x8 k0 = *(const bf16x8*)&k_cur[r0 * 256 + (cbs ^ ((r0 & 15) << 4))];
          bf16x8 k1 = *(const bf16x8*)&k_cur[r1 * 256 + (cbs ^ ((r1 & 15) << 4))];
          sa = mfma_32x32x16(k0, qf[ss], sa);
          sb = mfma_32x32x16(k1, qf[ss], sb);
        }
        __builtin_amdgcn_s_setprio(0);
        if (kv0 + 63 > qminw) {                  // causal mask (diagonal only)
#pragma unroll
          for (int jj = 0; jj < 16; ++jj) {
            int rr = (jj & 3) + 8 * (jj >> 2) + 4 * hi;
            sa[jj] = (kv0 + rr      > qrow) ? -1e30f : sa[jj];
            sb[jj] = (kv0 + 32 + rr > qrow) ? -1e30f : sb[jj];
          }
        }
        // no-max softmax: P = exp2(S); normalization deferred to epilogue.
#pragma unroll
        for (int jj = 0; jj < 16; ++jj) sa[jj] = fast_exp2(sa[jj]);
#pragma unroll
        for (int jj = 0; jj < 16; ++jj) sb[jj] = fast_exp2(sb[jj]);
#pragma unroll
        for (int jj = 0; jj < 16; ++jj) psum[jj] += sa[jj] + sb[jj];

        // PV: Y^T += V^T @ P^T; cross-half exchange via v_permlane32_swap_b32
#pragma unroll
        for (int a = 0; a < 2; ++a) {
          unsigned pk[8];
#pragma unroll
          for (int jj = 0; jj < 8; ++jj) {
            float lo  = a ? sb[2 * jj]     : sa[2 * jj];
            float hi2 = a ? sb[2 * jj + 1] : sa[2 * jj + 1];
            pk[jj] = pack2bf(lo, hi2);
          }
#pragma unroll
          for (int s2 = 0; s2 < 2; ++s2) {
            int base = 4 * s2;
            unsigned a0 = pk[base + 0], b0 = pk[base + 2];
            unsigned a1 = pk[base + 1], b1 = pk[base + 3];
            asm volatile("v_permlane32_swap_b32 %0, %1" : "+v"(a0), "+v"(b0));
            asm volatile("v_permlane32_swap_b32 %0, %1" : "+v"(a1), "+v"(b1));
            union { bf16x8 v; unsigned u[4]; } pf;
            pf.u[0] = a0;
            pf.u[1] = a1;
            pf.u[2] = b0;
            pf.u[3] = b1;
            __builtin_amdgcn_s_setprio(1);
#pragma unroll
            for (int dt = 0; dt < 4; ++dt) {
              int vrow = 32 * dt + l31;          // row = d
              int vcol = 128 * h + 64 * a + 32 * s2 + 16 * hi;
              bf16x8 vf = *(const bf16x8*)&v_cur[vrow * 256 +
                                                 (vcol ^ ((vrow & 15) << 4))];
              yacc[dt] = mfma_32x32x16(vf, pf.v, yacc[dt]);
            }
            __builtin_amdgcn_s_setprio(0);
          }
        }
      }
      // drain (free: next-tile loads issued a full compute interval ago)
      SBAR();
      asm volatile("s_waitcnt vmcnt(0)" ::: "memory");
      __builtin_amdgcn_s_barrier();
      SBAR();
      char* tmp = k_cur; k_cur = k_nxt; k_nxt = tmp;
      tmp = v_cur; v_cur = v_nxt; v_nxt = tmp;
    }

    // lsum = reduce(psum) + cross-half
    float lsum = 0.f;
#pragma unroll
    for (int jj = 0; jj < 16; ++jj) lsum += psum[jj];
    lsum += __shfl_xor(lsum, 32);

    float* ob = out + ((size_t)b * SEQ + qrow) * DM;
    const int row = wave * 32 + l31;   // 0..255 within tile
    if (mode == 0) {
      float inv = 1.0f / lsum;
#pragma unroll
      for (int dt = 0; dt < 4; ++dt) {
#pragma unroll
        for (int g2 = 0; g2 < 4; ++g2) {
          float4 v;
          v.x = yacc[dt][4 * g2 + 0] * inv;
          v.y = yacc[dt][4 * g2 + 1] * inv;
          v.z = yacc[dt][4 * g2 + 2] * inv;
          v.w = yacc[dt][4 * g2 + 3] * inv;
          *(float4*)&ob[32 * dt + 8 * g2 + 4 * hi] = v;
        }
      }
    } else if (mode == 1) {
#pragma unroll
      for (int dt = 0; dt < 4; ++dt) {
#pragma unroll
        for (int g2 = 0; g2 < 4; ++g2) {
          float4 v;
          v.x = yacc[dt][4 * g2 + 0];
          v.y = yacc[dt][4 * g2 + 1];
          v.z = yacc[dt][4 * g2 + 2];
          v.w = yacc[dt][4 * g2 + 3];
          *(float4*)&ob[32 * dt + 8 * g2 + 4 * hi] = v;
        }
      }
      if (hi == 0) lsumA[m * 256 + row] = lsum;
    } else {
      __hip_bfloat16* pb = partB + ((size_t)m * 256 + row) * DM;
#pragma unroll
      for (int dt = 0; dt < 4; ++dt) {
#pragma unroll
        for (int g2 = 0; g2 < 4; ++g2) {
          uint2 pv;
          pv.x = pack2bf(yacc[dt][4 * g2 + 0], yacc[dt][4 * g2 + 1]);
          pv.y = pack2bf(yacc[dt][4 * g2 + 2], yacc[dt][4 * g2 + 3]);
          *(uint2*)&pb[32 * dt + 8 * g2 + 4 * hi] = pv;
        }
      }
      if (hi == 0) lsumB[m * 256 + row] = lsum;
    }
  };

  if (!isB) {
    visit(bigQ, 0, 17, 1);
  } else {
    visit(bigQ, 17, 15 - 2 * i, 2);
    visit(i, 0, 2 * i + 2, 0);
  }
}

// ---------------------------------------------------------------------------
// Kernel 3: merge split tiles: out = (A_f32(out) + B_bf16(ws)) / (lsumA+lsumB)
//   128 slots x 256 rows x 128 d.
// ---------------------------------------------------------------------------
__global__ void __launch_bounds__(256)
merge(float* __restrict__ out, const float* __restrict__ lsumA,
      const float* __restrict__ lsumB, const __hip_bfloat16* __restrict__ partB) {
  __shared__ float invls[256];
  const int m = blockIdx.x;
  const int b = m >> 3;
  const int Q = 15 - (m & 7);          // big tile index (256-row tiles)
  const int tid = threadIdx.x;
  invls[tid] = 1.0f / (lsumA[m * 256 + tid] + lsumB[m * 256 + tid]);
  __syncthreads();
  float4* o4 = (float4*)(out + ((size_t)b * SEQ + (size_t)Q * 256) * DM);
  const __hip_bfloat16* pb = partB + (size_t)m * 256 * DM;
#pragma unroll
  for (int k = 0; k < 32; ++k) {
    int e4 = tid + 256 * k;            // 256 rows x 32 float4/row
    int row = e4 >> 5;
    float4 a = o4[e4];
    union { uint2 v; unsigned short s[4]; } pv;
    pv.v = *(const uint2*)&pb[e4 * 4];
    float inv = invls[row];
    float4 r;
    r.x = (a.x + us2f(pv.s[0])) * inv;
    r.y = (a.y + us2f(pv.s[1])) * inv;
    r.z = (a.z + us2f(pv.s[2])) * inv;
    r.w = (a.w + us2f(pv.s[3])) * inv;
    o4[e4] = r;
  }
}

extern "C" void kernel_launch(void* const* d_in, const int* in_sizes, int n_in,
                              void* d_out, int out_size, void* d_ws, size_t ws_size,
                              hipStream_t stream) {
  const float* x  = (const float*)d_in[0];
  const float* Wq = (const float*)d_in[1];
  const float* Wk = (const float*)d_in[2];
  const float* Wv = (const float*)d_in[3];
  float* out = (float*)d_out;

  char* ws = (char*)d_ws;
  __hip_bfloat16* qw    = (__hip_bfloat16*)(ws);
  __hip_bfloat16* kw    = (__hip_bfloat16*)(ws + (size_t)16 * 1024 * 1024);
  __hip_bfloat16* vtw   = (__hip_bfloat16*)(ws + (size_t)32 * 1024 * 1024);
  char* base48 = ws + (size_t)48 * 1024 * 1024;
  __hip_bfloat16* Wb    = (__hip_bfloat16*)(base48);                       // 96KB
  float*          lsumA = (float*)(base48 + (size_t)1 * 1024 * 1024);      // 128KB
  float*          lsumB = (float*)(base48 + (size_t)2 * 1024 * 1024);      // 128KB
  __hip_bfloat16* partB = (__hip_bfloat16*)(base48 + (size_t)3 * 1024 * 1024); // 8MB
  // total ws use: 48MB + 3MB + 8MB = 59MB (75MB proven to fit in R10/R12)

  prep_w<<<24, 256, 0, stream>>>(Wq, Wk, Wv, Wb);
  proj<<<512, 256, 0, stream>>>(x, Wb, qw, kw, vtw);
  attn<<<256, 512, 0, stream>>>(qw, kw, vtw, out, lsumA, lsumB, partB);
  merge<<<128, 256, 0, stream>>>(out, lsumA, lsumB, partB);
}